// Round 1
// baseline (25183.653 us; speedup 1.0000x reference)
//
#include <hip/hip_runtime.h>

#define B_   128
#define S_   1024
#define I_   256
#define H_   512
#define L1_  256
#define O_   64

#define NGRP 8     // batch groups (one per XCD ideally)
#define WGPG 32    // workgroups per group
#define MB   16    // batches per group
#define NH   16    // hidden units per WG
#define NCOL 64    // gate columns per WG (4 gates x NH)
#define SX   8     // K-steps for X part (256/32)
#define SH   16    // K-steps for H part (512/32)

typedef __attribute__((ext_vector_type(8))) short short8;
typedef __attribute__((ext_vector_type(4))) float f4;

__device__ __forceinline__ unsigned short f2bf(float x) {
  unsigned u = __builtin_bit_cast(unsigned, x);
  u += 0x7FFFu + ((u >> 16) & 1u);   // RNE
  return (unsigned short)(u >> 16);
}

__device__ __forceinline__ f4 mfma_bf16(short8 a, short8 b, f4 c) {
  // inline asm: robust to builtin signature (short8 vs bf16x8); gfx950 unified VGPR ok
  asm("v_mfma_f32_16x16x32_bf16 %0, %1, %2, %0" : "+v"(c) : "v"(a), "v"(b));
  return c;
}

// Persistent recurrent kernel: 256 WGs (LDS-forced 1/CU => co-resident), 256 thr.
__global__ __launch_bounds__(256, 1)
void lstm_rec(const float* __restrict__ X,
              const float* __restrict__ Wxi, const float* __restrict__ Whi, const float* __restrict__ bi,
              const float* __restrict__ Wxf, const float* __restrict__ Whf, const float* __restrict__ bfp,
              const float* __restrict__ Wxo, const float* __restrict__ Who, const float* __restrict__ bop,
              const float* __restrict__ Wxc, const float* __restrict__ Whc, const float* __restrict__ bcp,
              float* __restrict__ out, unsigned* __restrict__ cnt, unsigned short* __restrict__ Hbuf)
{
  // B-fragment layout for v_mfma_f32_16x16x32_bf16: element (k,c) -> lane=((k&31)>>3)*16+c, e=k&7
  __shared__ unsigned short WhF[4][SH][64][8];  // 64 KB
  __shared__ unsigned short WxF[4][SX][64][8];  // 32 KB
  __shared__ unsigned short As[SX + SH][64][8]; // 24 KB  A-fragments (X | H)
  __shared__ float Ps[MB][NCOL];                // 4 KB   pre-activations
  __shared__ float bias_s[NCOL];

  const int tid  = threadIdx.x;
  const int lane = tid & 63;
  const int wv   = tid >> 6;        // wave id == gate id
  const int g    = blockIdx.x & 7;  // batch group
  const int jg   = blockIdx.x >> 3; // hidden block 0..31
  const int j0   = jg * NH;
  const int b0   = g * MB;

  const float* Whg[4] = {Whi, Whf, Who, Whc};
  const float* Wxg[4] = {Wxi, Wxf, Wxo, Wxc};
  const float* bg[4]  = {bi, bfp, bop, bcp};

  // ---- one-time: pack weight slices into LDS as bf16 B-fragments ----
  for (int gate = 0; gate < 4; ++gate) {
    const float* Wp = Whg[gate];
    for (int it = 0; it < 32; ++it) {          // 512*16/256
      int idx = it * 256 + tid;
      int k = idx >> 4, c = idx & 15;
      WhF[gate][k >> 5][((k & 31) >> 3) * 16 + c][k & 7] = f2bf(Wp[(size_t)k * H_ + j0 + c]);
    }
    const float* Xp = Wxg[gate];
    for (int it = 0; it < 16; ++it) {          // 256*16/256
      int idx = it * 256 + tid;
      int k = idx >> 4, c = idx & 15;
      WxF[gate][k >> 5][((k & 31) >> 3) * 16 + c][k & 7] = f2bf(Xp[(size_t)k * H_ + j0 + c]);
    }
  }
  if (tid < NCOL) bias_s[tid] = bg[tid >> 4][j0 + (tid & 15)];
  __syncthreads();

  float Creg = 0.f;                 // thread owns cell state for (pb, ph)
  const int pb = tid >> 4;
  const int ph = tid & 15;
  unsigned* mycnt = cnt + g * 32;   // 128B apart per group

  for (int t = 0; t < S_; ++t) {
    // ---- stage X_t into A-fragments (H-independent: do before the barrier) ----
    #pragma unroll
    for (int it = 0; it < 4; ++it) {
      int fidx = it * 256 + tid;            // float4 index, 16 rows x 64
      int row = fidx >> 6, c4 = fidx & 63;
      const float4* src = (const float4*)(X + ((size_t)(b0 + row) * S_ + t) * I_) + c4;
      float4 v = *src;
      int k0 = c4 * 4;
      unsigned short* dst = &As[k0 >> 5][((k0 & 31) >> 3) * 16 + row][k0 & 7];
      dst[0] = f2bf(v.x); dst[1] = f2bf(v.y); dst[2] = f2bf(v.z); dst[3] = f2bf(v.w);
    }
    // ---- wait for H_t, then stage it ----
    if (t > 0) {
      const unsigned target = (unsigned)(WGPG * t);
      while (__hip_atomic_load(mycnt, __ATOMIC_RELAXED, __HIP_MEMORY_SCOPE_AGENT) < target)
        __builtin_amdgcn_s_sleep(1);
      __threadfence();  // acquire: invalidate stale L1/L2 copies of Hbuf
      const unsigned short* Hsrc = Hbuf + (size_t)(t & 1) * B_ * H_;
      #pragma unroll
      for (int it = 0; it < 4; ++it) {
        int hidx = it * 256 + tid;          // ushort8 index, 16 rows x 64
        int row = hidx >> 6, c8 = hidx & 63;
        int k0 = c8 * 8;
        short8 hv = *(const short8*)(Hsrc + (size_t)(b0 + row) * H_ + k0);
        *(short8*)&As[SX + (k0 >> 5)][((k0 & 31) >> 3) * 16 + row][0] = hv;
      }
    }
    __syncthreads();

    // ---- P[16,64] = [X_t | H_t] @ [Wx; Wh] + bias   (wave wv computes gate wv) ----
    float bv = bias_s[wv * 16 + (lane & 15)];
    f4 acc = {bv, bv, bv, bv};
    asm("s_nop 1" : "+v"(acc));  // VALU->MFMA srcC hazard guard
    #pragma unroll
    for (int s = 0; s < SX; ++s) {
      short8 a = *(const short8*)&As[s][lane][0];
      short8 b = *(const short8*)&WxF[wv][s][lane][0];
      acc = mfma_bf16(a, b, acc);
    }
    if (t > 0) {
      #pragma unroll
      for (int s = 0; s < SH; ++s) {
        short8 a = *(const short8*)&As[SX + s][lane][0];
        short8 b = *(const short8*)&WhF[wv][s][lane][0];
        acc = mfma_bf16(a, b, acc);
      }
    }
    asm("s_nop 7\n\ts_nop 7" : "+v"(acc));  // MFMA->VALU read hazard guard
    {
      int col = wv * 16 + (lane & 15);
      int r0 = (lane >> 4) * 4;             // C/D: col=lane&15, row=(lane>>4)*4+e
      Ps[r0 + 0][col] = acc[0];
      Ps[r0 + 1][col] = acc[1];
      Ps[r0 + 2][col] = acc[2];
      Ps[r0 + 3][col] = acc[3];
    }
    __syncthreads();

    // ---- pointwise gates (fp32), update C (register), emit H_{t+1} ----
    {
      float pi = Ps[pb][ph];
      float pf = Ps[pb][16 + ph];
      float po = Ps[pb][32 + ph];
      float pc = Ps[pb][48 + ph];
      float Ig = 1.f / (1.f + __expf(-pi));
      float Fg = 1.f / (1.f + __expf(-pf));
      float Og = 1.f / (1.f + __expf(-po));
      float Ct = 1.f - 2.f / (__expf(2.f * pc) + 1.f);   // tanh
      float Cn = Fg * Creg + Ig * Ct;
      Creg = Cn;
      float Hn = (1.f - 2.f / (__expf(2.f * Cn) + 1.f)) + Og;  // tanh(C) + O (addition!)
      unsigned short* Hdst = Hbuf + (size_t)((t + 1) & 1) * B_ * H_;
      Hdst[(size_t)(b0 + pb) * H_ + j0 + ph] = f2bf(Hn);
      if (t == S_ - 1) {
        out[B_ * O_ + (size_t)(b0 + pb) * H_ + j0 + ph] = Hn;            // Hf (fp32)
        out[B_ * O_ + B_ * H_ + (size_t)(b0 + pb) * H_ + j0 + ph] = Cn;  // Cf (fp32)
      }
    }
    if (t < S_ - 1) {
      __syncthreads();              // drains all waves' Hdst stores (vmcnt 0 at barrier)
      if (tid == 0) {
        __threadfence();            // release: wbl2 -> LLC
        __hip_atomic_fetch_add(mycnt, 1u, __ATOMIC_RELAXED, __HIP_MEMORY_SCOPE_AGENT);
      }
    }
  }
}

// Output head: h1 = relu(Hf@W_o1+b_o1); out = softmax(h1@W_o2+b_o2). One WG per batch row.
__global__ __launch_bounds__(256, 1)
void lstm_head(const float* __restrict__ Hf,
               const float* __restrict__ Wo1, const float* __restrict__ bo1,
               const float* __restrict__ Wo2, const float* __restrict__ bo2,
               float* __restrict__ outp)
{
  __shared__ float hf[H_];
  __shared__ float h1[L1_];
  const int tid = threadIdx.x;
  const int b = blockIdx.x;
  hf[tid]       = Hf[(size_t)b * H_ + tid];
  hf[tid + 256] = Hf[(size_t)b * H_ + tid + 256];
  __syncthreads();
  float a = bo1[tid];
  #pragma unroll 8
  for (int k = 0; k < H_; ++k) a = fmaf(hf[k], Wo1[(size_t)k * L1_ + tid], a);
  h1[tid] = fmaxf(a, 0.f);
  __syncthreads();
  if (tid < O_) {
    float l = bo2[tid];
    #pragma unroll 8
    for (int j = 0; j < L1_; ++j) l = fmaf(h1[j], Wo2[(size_t)j * O_ + tid], l);
    float m = l;
    #pragma unroll
    for (int off = 32; off > 0; off >>= 1) m = fmaxf(m, __shfl_xor(m, off, 64));
    float e = __expf(l - m);
    float ssum = e;
    #pragma unroll
    for (int off = 32; off > 0; off >>= 1) ssum += __shfl_xor(ssum, off, 64);
    outp[(size_t)b * O_ + tid] = e / ssum;
  }
}

extern "C" void kernel_launch(void* const* d_in, const int* in_sizes, int n_in,
                              void* d_out, int out_size, void* d_ws, size_t ws_size,
                              hipStream_t stream) {
  (void)in_sizes; (void)n_in; (void)out_size; (void)ws_size;
  const float* X   = (const float*)d_in[0];
  const float* Wxi = (const float*)d_in[1];
  const float* Whi = (const float*)d_in[2];
  const float* bi  = (const float*)d_in[3];
  const float* Wxf = (const float*)d_in[4];
  const float* Whf = (const float*)d_in[5];
  const float* bfv = (const float*)d_in[6];
  const float* Wxo = (const float*)d_in[7];
  const float* Who = (const float*)d_in[8];
  const float* bo  = (const float*)d_in[9];
  const float* Wxc = (const float*)d_in[10];
  const float* Whc = (const float*)d_in[11];
  const float* bc  = (const float*)d_in[12];
  const float* Wo1 = (const float*)d_in[13];
  const float* bo1 = (const float*)d_in[14];
  const float* Wo2 = (const float*)d_in[15];
  const float* bo2 = (const float*)d_in[16];
  float* out = (float*)d_out;

  unsigned*       cnt  = (unsigned*)d_ws;                         // 1 KB of counters
  unsigned short* Hbuf = (unsigned short*)((char*)d_ws + 1024);   // 2 x 128 x 512 bf16

  hipMemsetAsync(d_ws, 0, 1024, stream);  // reset barrier counters every call
  hipLaunchKernelGGL(lstm_rec, dim3(NGRP * WGPG), dim3(256), 0, stream,
                     X, Wxi, Whi, bi, Wxf, Whf, bfv, Wxo, Who, bo, Wxc, Whc, bc,
                     out, cnt, Hbuf);
  hipLaunchKernelGGL(lstm_head, dim3(B_), dim3(256), 0, stream,
                     out + B_ * O_, Wo1, bo1, Wo2, bo2, out);
}

// Round 2
// 5805.537 us; speedup vs baseline: 4.3379x; 4.3379x over previous
//
#include <hip/hip_runtime.h>

#define B_   128
#define S_   1024
#define I_   256
#define H_   512
#define L1_  256
#define O_   64

#define NGRP 8     // batch groups (one per XCD if dispatch round-robins)
#define WGPG 32    // workgroups per group (cohort that must sync per step)
#define MB   16    // batches per group
#define NH   16    // hidden units per WG
#define NCOL 64    // gate columns per WG (4 gates x NH)
#define SX   8     // K-steps for X part (256/32)
#define SH   16    // K-steps for H part (512/32)

typedef __attribute__((ext_vector_type(8))) short short8;
typedef __attribute__((ext_vector_type(4))) float f4;

__device__ __forceinline__ unsigned short f2bf(float x) {
  unsigned u = __builtin_bit_cast(unsigned, x);
  u += 0x7FFFu + ((u >> 16) & 1u);   // RNE
  return (unsigned short)(u >> 16);
}

__device__ __forceinline__ f4 mfma_bf16(short8 a, short8 b, f4 c) {
  asm("v_mfma_f32_16x16x32_bf16 %0, %1, %2, %0" : "+v"(c) : "v"(a), "v"(b));
  return c;
}

// Persistent recurrent kernel: 256 WGs (LDS-forced 1/CU => co-resident), 256 thr.
// H exchange through LLC via relaxed agent-scope atomics; NO threadfence anywhere
// (threadfence = buffer_wbl2 + buffer_inv on gfx950 -> ~20us/step of L2 flushing, R1 lesson).
__global__ __launch_bounds__(256, 1)
void lstm_rec(const float* __restrict__ X,
              const float* __restrict__ Wxi, const float* __restrict__ Whi, const float* __restrict__ bi,
              const float* __restrict__ Wxf, const float* __restrict__ Whf, const float* __restrict__ bfp,
              const float* __restrict__ Wxo, const float* __restrict__ Who, const float* __restrict__ bop,
              const float* __restrict__ Wxc, const float* __restrict__ Whc, const float* __restrict__ bcp,
              float* __restrict__ out, unsigned* __restrict__ cnt, unsigned* __restrict__ Hbuf)
{
  // B-fragment layout for v_mfma_f32_16x16x32_bf16: element (k,c) -> lane=((k&31)>>3)*16+c, e=k&7
  __shared__ unsigned short WhF[4][SH][64][8];  // 64 KB
  __shared__ unsigned short WxF[4][SX][64][8];  // 32 KB
  __shared__ unsigned short As[SX + SH][64][8]; // 24 KB  A-fragments (X | H)
  __shared__ float Ps[MB][NCOL];                // 4 KB   pre-activations
  __shared__ float bias_s[NCOL];

  const int tid  = threadIdx.x;
  const int lane = tid & 63;
  const int wv   = tid >> 6;        // wave id == gate id
  const int g    = blockIdx.x & 7;  // batch group
  const int jg   = blockIdx.x >> 3; // hidden block 0..31
  const int j0   = jg * NH;
  const int b0   = g * MB;

  const float* Whg[4] = {Whi, Whf, Who, Whc};
  const float* Wxg[4] = {Wxi, Wxf, Wxo, Wxc};
  const float* bg[4]  = {bi, bfp, bop, bcp};

  // ---- one-time: pack weight slices into LDS as bf16 B-fragments ----
  for (int gate = 0; gate < 4; ++gate) {
    const float* Wp = Whg[gate];
    for (int it = 0; it < 32; ++it) {          // 512*16/256
      int idx = it * 256 + tid;
      int k = idx >> 4, c = idx & 15;
      WhF[gate][k >> 5][((k & 31) >> 3) * 16 + c][k & 7] = f2bf(Wp[(size_t)k * H_ + j0 + c]);
    }
    const float* Xp = Wxg[gate];
    for (int it = 0; it < 16; ++it) {          // 256*16/256
      int idx = it * 256 + tid;
      int k = idx >> 4, c = idx & 15;
      WxF[gate][k >> 5][((k & 31) >> 3) * 16 + c][k & 7] = f2bf(Xp[(size_t)k * H_ + j0 + c]);
    }
  }
  if (tid < NCOL) bias_s[tid] = bg[tid >> 4][j0 + (tid & 15)];
  __syncthreads();

  float Creg = 0.f;                 // thread owns cell state for (pb, ph)
  const int pb = tid >> 4;
  const int ph = tid & 15;
  unsigned* mycnt = cnt + g * 32;   // 128B apart per group

  for (int t = 0; t < S_; ++t) {
    // ---- stage X_t into A-fragments (H-independent) ----
    #pragma unroll
    for (int it = 0; it < 4; ++it) {
      int fidx = it * 256 + tid;            // float4 index, 16 rows x 64
      int row = fidx >> 6, c4 = fidx & 63;
      const float4* src = (const float4*)(X + ((size_t)(b0 + row) * S_ + t) * I_) + c4;
      float4 v = *src;
      int k0 = c4 * 4;
      unsigned short* dst = &As[k0 >> 5][((k0 & 31) >> 3) * 16 + row][k0 & 7];
      dst[0] = f2bf(v.x); dst[1] = f2bf(v.y); dst[2] = f2bf(v.z); dst[3] = f2bf(v.w);
    }
    __syncthreads();   // A: As-X ready (prev-step As readers drained at prev syncs)

    // ---- X-part MFMAs first: off the post-poll critical path ----
    float bv = bias_s[wv * 16 + (lane & 15)];
    f4 acc = {bv, bv, bv, bv};
    asm("s_nop 1" : "+v"(acc));  // VALU->MFMA srcC hazard guard
    #pragma unroll
    for (int s = 0; s < SX; ++s) {
      short8 a = *(const short8*)&As[s][lane][0];
      short8 b = *(const short8*)&WxF[wv][s][lane][0];
      acc = mfma_bf16(a, b, acc);
    }

    // ---- wait for H_t (LLC flag), then stage it from LLC via agent atomics ----
    if (t > 0) {
      const unsigned target = (unsigned)(WGPG * t);
      while (__hip_atomic_load(mycnt, __ATOMIC_RELAXED, __HIP_MEMORY_SCOPE_AGENT) < target)
        __builtin_amdgcn_s_sleep(1);
      asm volatile("" ::: "memory");  // compile-time ordering only; no cache ops
      const unsigned* Hsrc = Hbuf + (size_t)(t & 1) * B_ * (H_ / 2);
      #pragma unroll
      for (int it = 0; it < 16; ++it) {
        int idx = it * 256 + tid;           // uint index: 16 rows x 256
        int row = idx >> 8, c = idx & 255;  // uint c holds H elems 2c, 2c+1
        unsigned hv = __hip_atomic_load(Hsrc + (size_t)(b0 + row) * (H_ / 2) + c,
                                        __ATOMIC_RELAXED, __HIP_MEMORY_SCOPE_AGENT);
        int k = 2 * c;                      // even -> 4B-aligned slot in fragment
        *(unsigned*)&As[SX + (k >> 5)][((k & 31) >> 3) * 16 + row][k & 7] = hv;
      }
    }
    __syncthreads();   // B: As-H ready

    // ---- H-part MFMAs ----
    if (t > 0) {
      #pragma unroll
      for (int s = 0; s < SH; ++s) {
        short8 a = *(const short8*)&As[SX + s][lane][0];
        short8 b = *(const short8*)&WhF[wv][s][lane][0];
        acc = mfma_bf16(a, b, acc);
      }
    }
    asm("s_nop 7\n\ts_nop 7" : "+v"(acc));  // MFMA->VALU read hazard guard
    {
      int col = wv * 16 + (lane & 15);
      int r0 = (lane >> 4) * 4;             // C/D: col=lane&15, row=(lane>>4)*4+e
      Ps[r0 + 0][col] = acc[0];
      Ps[r0 + 1][col] = acc[1];
      Ps[r0 + 2][col] = acc[2];
      Ps[r0 + 3][col] = acc[3];
    }
    __syncthreads();   // C: Ps ready

    // ---- pointwise gates (fp32), update C (register), emit H_{t+1} ----
    {
      float pi = Ps[pb][ph];
      float pf = Ps[pb][16 + ph];
      float po = Ps[pb][32 + ph];
      float pc = Ps[pb][48 + ph];
      float Ig = 1.f / (1.f + __expf(-pi));
      float Fg = 1.f / (1.f + __expf(-pf));
      float Og = 1.f / (1.f + __expf(-po));
      float Ct = 1.f - 2.f / (__expf(2.f * pc) + 1.f);   // tanh
      float Cn = Fg * Creg + Ig * Ct;
      Creg = Cn;
      float Hn = (1.f - 2.f / (__expf(2.f * Cn) + 1.f)) + Og;  // tanh(C) + O (addition!)
      if (t < S_ - 1) {
        // pack 2 bf16 per uint with lane neighbor; even-ph lanes store
        unsigned hb = f2bf(Hn);
        unsigned other = (unsigned)__shfl_xor((int)hb, 1, 64);
        if ((ph & 1) == 0) {
          unsigned packed = hb | (other << 16);   // low half = even H index
          unsigned* Hdst = Hbuf + (size_t)((t + 1) & 1) * B_ * (H_ / 2);
          __hip_atomic_store(Hdst + (size_t)(b0 + pb) * (H_ / 2) + jg * 8 + (ph >> 1),
                             packed, __ATOMIC_RELAXED, __HIP_MEMORY_SCOPE_AGENT);
        }
      } else {
        out[B_ * O_ + (size_t)(b0 + pb) * H_ + j0 + ph] = Hn;            // Hf (fp32)
        out[B_ * O_ + B_ * H_ + (size_t)(b0 + pb) * H_ + j0 + ph] = Cn;  // Cf (fp32)
      }
    }
    if (t < S_ - 1) {
      __syncthreads();              // D: drains all waves' H stores (vmcnt 0 at barrier)
      if (tid == 0)
        __hip_atomic_fetch_add(mycnt, 1u, __ATOMIC_RELAXED, __HIP_MEMORY_SCOPE_AGENT);
    }
  }
}

// Output head: h1 = relu(Hf@W_o1+b_o1); out = softmax(h1@W_o2+b_o2). One WG per batch row.
__global__ __launch_bounds__(256, 1)
void lstm_head(const float* __restrict__ Hf,
               const float* __restrict__ Wo1, const float* __restrict__ bo1,
               const float* __restrict__ Wo2, const float* __restrict__ bo2,
               float* __restrict__ outp)
{
  __shared__ float hf[H_];
  __shared__ float h1[L1_];
  const int tid = threadIdx.x;
  const int b = blockIdx.x;
  hf[tid]       = Hf[(size_t)b * H_ + tid];
  hf[tid + 256] = Hf[(size_t)b * H_ + tid + 256];
  __syncthreads();
  float a = bo1[tid];
  #pragma unroll 8
  for (int k = 0; k < H_; ++k) a = fmaf(hf[k], Wo1[(size_t)k * L1_ + tid], a);
  h1[tid] = fmaxf(a, 0.f);
  __syncthreads();
  if (tid < O_) {
    float l = bo2[tid];
    #pragma unroll 8
    for (int j = 0; j < L1_; ++j) l = fmaf(h1[j], Wo2[(size_t)j * O_ + tid], l);
    float m = l;
    #pragma unroll
    for (int off = 32; off > 0; off >>= 1) m = fmaxf(m, __shfl_xor(m, off, 64));
    float e = __expf(l - m);
    float ssum = e;
    #pragma unroll
    for (int off = 32; off > 0; off >>= 1) ssum += __shfl_xor(ssum, off, 64);
    outp[(size_t)b * O_ + tid] = e / ssum;
  }
}

extern "C" void kernel_launch(void* const* d_in, const int* in_sizes, int n_in,
                              void* d_out, int out_size, void* d_ws, size_t ws_size,
                              hipStream_t stream) {
  (void)in_sizes; (void)n_in; (void)out_size; (void)ws_size;
  const float* X   = (const float*)d_in[0];
  const float* Wxi = (const float*)d_in[1];
  const float* Whi = (const float*)d_in[2];
  const float* bi  = (const float*)d_in[3];
  const float* Wxf = (const float*)d_in[4];
  const float* Whf = (const float*)d_in[5];
  const float* bfv = (const float*)d_in[6];
  const float* Wxo = (const float*)d_in[7];
  const float* Who = (const float*)d_in[8];
  const float* bo  = (const float*)d_in[9];
  const float* Wxc = (const float*)d_in[10];
  const float* Whc = (const float*)d_in[11];
  const float* bc  = (const float*)d_in[12];
  const float* Wo1 = (const float*)d_in[13];
  const float* bo1 = (const float*)d_in[14];
  const float* Wo2 = (const float*)d_in[15];
  const float* bo2 = (const float*)d_in[16];
  float* out = (float*)d_out;

  unsigned* cnt  = (unsigned*)d_ws;                        // 1 KB of counters
  unsigned* Hbuf = (unsigned*)((char*)d_ws + 1024);        // 2 x 128 x 256 uints (2xbf16 each)

  hipMemsetAsync(d_ws, 0, 1024, stream);  // reset barrier counters every call
  hipLaunchKernelGGL(lstm_rec, dim3(NGRP * WGPG), dim3(256), 0, stream,
                     X, Wxi, Whi, bi, Wxf, Whf, bfv, Wxo, Who, bo, Wxc, Whc, bc,
                     out, cnt, Hbuf);
  hipLaunchKernelGGL(lstm_head, dim3(B_), dim3(256), 0, stream,
                     out + B_ * O_, Wo1, bo1, Wo2, bo2, out);
}

// Round 3
// 2702.791 us; speedup vs baseline: 9.3176x; 2.1480x over previous
//
#include <hip/hip_runtime.h>

#define B_   128
#define S_   1024
#define I_   256
#define H_   512
#define L1_  256
#define O_   64

#define NGRP 8     // batch groups
#define WGPG 32    // workgroups per group (sync cohort)
#define MB   16    // batches per group
#define NH   16    // hidden units per WG
#define NCOL 64    // gate columns per WG (4 gates x NH)
#define SX   8     // K-steps for X part (256/32)
#define SH   16    // K-steps for H part (512/32)

#define HB_UINTS_PER_BUF 32768   // 8 groups x 4096 uints (16KB fragment image per group)

typedef __attribute__((ext_vector_type(8))) short short8;
typedef __attribute__((ext_vector_type(4))) float f4;
typedef __attribute__((ext_vector_type(4))) unsigned u32x4;

__device__ __forceinline__ unsigned short f2bf(float x) {
  unsigned u = __builtin_bit_cast(unsigned, x);
  u += 0x7FFFu + ((u >> 16) & 1u);   // RNE
  return (unsigned short)(u >> 16);
}

__device__ __forceinline__ f4 mfma_bf16(short8 a, short8 b, f4 c) {
  asm("v_mfma_f32_16x16x32_bf16 %0, %1, %2, %0" : "+v"(c) : "v"(a), "v"(b));
  return c;
}

// Persistent recurrent kernel: 256 WGs (LDS-forced 1/CU => co-resident), 256 thr.
// H exchange: producer writes bf16 H directly in MFMA A-fragment order to a
// group-local 16KB region at the LLC (relaxed agent atomics); consumer copies it
// with sc0+sc1 dwordx4 loads (LLC-fresh) and LINEAR ds_write_b128 (0 conflicts).
// Sync: per-WG flag slots (no RMW); wave0 polls via 32-lane ballot; LDS relay.
__global__ __launch_bounds__(256, 1)
void lstm_rec(const float* __restrict__ X,
              const float* __restrict__ Wxi, const float* __restrict__ Whi, const float* __restrict__ bi,
              const float* __restrict__ Wxf, const float* __restrict__ Whf, const float* __restrict__ bfp,
              const float* __restrict__ Wxo, const float* __restrict__ Who, const float* __restrict__ bop,
              const float* __restrict__ Wxc, const float* __restrict__ Whc, const float* __restrict__ bcp,
              float* __restrict__ out, unsigned* __restrict__ flags, unsigned* __restrict__ Hbuf)
{
  // Fragment layout for v_mfma_f32_16x16x32_bf16 (verified numerically in R1/R2):
  //   element (k, col) -> lane = ((k&31)>>3)*16 + col, e = k&7;  As[s][lane][e], s = k>>5.
  __shared__ unsigned short WhF[4][SH][64][8];  // 64 KB
  __shared__ unsigned short WxF[4][SX][64][8];  // 32 KB
  __shared__ unsigned short As[SX + SH][64][8]; // 24 KB  A-fragments (X | H)
  __shared__ float Ps[MB][NCOL];                // 4 KB   pre-activations
  __shared__ float bias_s[NCOL];
  __shared__ int go_s;

  const int tid  = threadIdx.x;
  const int lane = tid & 63;
  const int wv   = tid >> 6;        // wave id == gate id
  const int g    = blockIdx.x & 7;  // batch group
  const int jg   = blockIdx.x >> 3; // hidden block 0..31
  const int j0   = jg * NH;
  const int b0   = g * MB;

  const float* Whg[4] = {Whi, Whf, Who, Whc};
  const float* Wxg[4] = {Wxi, Wxf, Wxo, Wxc};
  const float* bg[4]  = {bi, bfp, bop, bcp};

  // ---- one-time: pack weight slices into LDS as bf16 B-fragments ----
  for (int gate = 0; gate < 4; ++gate) {
    const float* Wp = Whg[gate];
    for (int it = 0; it < 32; ++it) {
      int idx = it * 256 + tid;
      int k = idx >> 4, c = idx & 15;
      WhF[gate][k >> 5][((k & 31) >> 3) * 16 + c][k & 7] = f2bf(Wp[(size_t)k * H_ + j0 + c]);
    }
    const float* Xp = Wxg[gate];
    for (int it = 0; it < 16; ++it) {
      int idx = it * 256 + tid;
      int k = idx >> 4, c = idx & 15;
      WxF[gate][k >> 5][((k & 31) >> 3) * 16 + c][k & 7] = f2bf(Xp[(size_t)k * H_ + j0 + c]);
    }
  }
  if (tid < NCOL) bias_s[tid] = bg[tid >> 4][j0 + (tid & 15)];
  if (tid == 0) go_s = 0;
  __syncthreads();

  float Creg = 0.f;                 // thread owns cell state for (pb, ph)
  const int pb = tid >> 4;
  const int ph = tid & 15;
  unsigned* myflags = flags + g * 32;   // group flag line (32 x 4B)

  for (int t = 0; t < S_; ++t) {
    // ---- stage X_t as A-fragments: one contiguous 16B chunk per thread-iter ----
    // chunk idx -> s=idx>>6, pos=idx&63, row=pos&15, posk=pos>>4, k0=s*32+posk*8
    #pragma unroll
    for (int it = 0; it < 2; ++it) {
      int idx = it * 256 + tid;             // 0..511
      int s = idx >> 6, pos = idx & 63;
      int row = pos & 15, k0 = s * 32 + (pos >> 4) * 8;
      const float* src = X + ((size_t)(b0 + row) * S_ + t) * I_ + k0;
      float4 v0 = *(const float4*)(src);
      float4 v1 = *(const float4*)(src + 4);
      union { unsigned short us[8]; u32x4 v; } pk;
      pk.us[0] = f2bf(v0.x); pk.us[1] = f2bf(v0.y); pk.us[2] = f2bf(v0.z); pk.us[3] = f2bf(v0.w);
      pk.us[4] = f2bf(v1.x); pk.us[5] = f2bf(v1.y); pk.us[6] = f2bf(v1.z); pk.us[7] = f2bf(v1.w);
      *(u32x4*)&As[s][pos][0] = pk.v;       // linear 16B/lane -> conflict-free
    }
    __syncthreads();   // A: As-X ready (prev readers drained at prev barriers)

    // ---- X-part MFMAs first: fills the poll-wait shadow ----
    float bv = bias_s[wv * 16 + (lane & 15)];
    f4 acc = {bv, bv, bv, bv};
    asm("s_nop 1" : "+v"(acc));  // VALU->MFMA srcC hazard guard
    #pragma unroll
    for (int s = 0; s < SX; ++s) {
      short8 a = *(const short8*)&As[s][lane][0];
      short8 b = *(const short8*)&WxF[wv][s][lane][0];
      acc = mfma_bf16(a, b, acc);
    }

    // ---- wait for H_t; wave0 polls flags, relays via LDS ----
    if (t > 0) {
      if (wv == 0) {
        const unsigned target = (unsigned)t;
        for (;;) {
          unsigned v = __hip_atomic_load(myflags + (lane & 31),
                                         __ATOMIC_RELAXED, __HIP_MEMORY_SCOPE_AGENT);
          if (__all(v >= target)) break;
          __builtin_amdgcn_s_sleep(1);
        }
        if (lane == 0) *(volatile int*)&go_s = t;
      } else {
        while (*(volatile int*)&go_s < t) __builtin_amdgcn_s_sleep(1);
      }
      // ---- copy group H fragment image (16KB) LLC -> LDS, fully linear ----
      const u32x4* gp = (const u32x4*)(Hbuf + (size_t)(t & 1) * HB_UINTS_PER_BUF + g * 4096);
      u32x4 r0, r1, r2, r3;
      asm volatile(
        "global_load_dwordx4 %0, %4, off sc0 sc1\n\t"
        "global_load_dwordx4 %1, %5, off sc0 sc1\n\t"
        "global_load_dwordx4 %2, %6, off sc0 sc1\n\t"
        "global_load_dwordx4 %3, %7, off sc0 sc1\n\t"
        "s_waitcnt vmcnt(0)"
        : "=&v"(r0), "=&v"(r1), "=&v"(r2), "=&v"(r3)
        : "v"(gp + tid), "v"(gp + tid + 256), "v"(gp + tid + 512), "v"(gp + tid + 768)
        : "memory");
      u32x4* lp = (u32x4*)&As[SX][0][0];
      lp[tid]       = r0;
      lp[tid + 256] = r1;
      lp[tid + 512] = r2;
      lp[tid + 768] = r3;
    }
    __syncthreads();   // B: As-H ready

    // ---- H-part MFMAs ----
    if (t > 0) {
      #pragma unroll
      for (int s = 0; s < SH; ++s) {
        short8 a = *(const short8*)&As[SX + s][lane][0];
        short8 b = *(const short8*)&WhF[wv][s][lane][0];
        acc = mfma_bf16(a, b, acc);
      }
    }
    asm("s_nop 7\n\ts_nop 7" : "+v"(acc));  // MFMA->VALU read hazard guard
    {
      int col = wv * 16 + (lane & 15);
      int r0 = (lane >> 4) * 4;             // C/D: col=lane&15, row=(lane>>4)*4+e
      Ps[r0 + 0][col] = acc[0];
      Ps[r0 + 1][col] = acc[1];
      Ps[r0 + 2][col] = acc[2];
      Ps[r0 + 3][col] = acc[3];
    }
    __syncthreads();   // C: Ps ready

    // ---- pointwise gates (fp32), update C (register), emit H_{t+1} ----
    {
      float pi = Ps[pb][ph];
      float pf = Ps[pb][16 + ph];
      float po = Ps[pb][32 + ph];
      float pc = Ps[pb][48 + ph];
      float Ig = 1.f / (1.f + __expf(-pi));
      float Fg = 1.f / (1.f + __expf(-pf));
      float Og = 1.f / (1.f + __expf(-po));
      float Ct = 1.f - 2.f / (__expf(2.f * pc) + 1.f);   // tanh
      float Cn = Fg * Creg + Ig * Ct;
      Creg = Cn;
      float Hn = (1.f - 2.f / (__expf(2.f * Cn) + 1.f)) + Og;  // tanh(C) + O (addition!)
      if (t < S_ - 1) {
        // store H in A-fragment order: j = jg*16+ph -> s=jg>>1, posk=(jg&1)*2+(ph>>3),
        // pos=posk*16+pb, e=ph&7. Pack (even,odd) e-pair via lane partner.
        unsigned hb = f2bf(Hn);
        unsigned other = (unsigned)__shfl_xor((int)hb, 1, 64);
        if ((ph & 1) == 0) {
          unsigned packed = hb | (other << 16);   // low half = even e
          int sl = jg >> 1;
          int pos = ((jg & 1) * 2 + (ph >> 3)) * 16 + pb;
          unsigned* dst = Hbuf + (size_t)((t + 1) & 1) * HB_UINTS_PER_BUF + g * 4096
                        + (sl * 64 + pos) * 4 + ((ph & 7) >> 1);
          __hip_atomic_store(dst, packed, __ATOMIC_RELAXED, __HIP_MEMORY_SCOPE_AGENT);
        }
      } else {
        out[B_ * O_ + (size_t)(b0 + pb) * H_ + j0 + ph] = Hn;            // Hf (fp32)
        out[B_ * O_ + B_ * H_ + (size_t)(b0 + pb) * H_ + j0 + ph] = Cn;  // Cf (fp32)
      }
    }
    if (t < S_ - 1) {
      __syncthreads();              // D: all waves' H stores drained (vmcnt 0 at barrier)
      if (tid == 0)
        __hip_atomic_store(myflags + jg, (unsigned)(t + 1),
                           __ATOMIC_RELAXED, __HIP_MEMORY_SCOPE_AGENT);
    }
  }
}

// Output head: h1 = relu(Hf@W_o1+b_o1); out = softmax(h1@W_o2+b_o2). One WG per batch row.
__global__ __launch_bounds__(256, 1)
void lstm_head(const float* __restrict__ Hf,
               const float* __restrict__ Wo1, const float* __restrict__ bo1,
               const float* __restrict__ Wo2, const float* __restrict__ bo2,
               float* __restrict__ outp)
{
  __shared__ float hf[H_];
  __shared__ float h1[L1_];
  const int tid = threadIdx.x;
  const int b = blockIdx.x;
  hf[tid]       = Hf[(size_t)b * H_ + tid];
  hf[tid + 256] = Hf[(size_t)b * H_ + tid + 256];
  __syncthreads();
  float a = bo1[tid];
  #pragma unroll 8
  for (int k = 0; k < H_; ++k) a = fmaf(hf[k], Wo1[(size_t)k * L1_ + tid], a);
  h1[tid] = fmaxf(a, 0.f);
  __syncthreads();
  if (tid < O_) {
    float l = bo2[tid];
    #pragma unroll 8
    for (int j = 0; j < L1_; ++j) l = fmaf(h1[j], Wo2[(size_t)j * O_ + tid], l);
    float m = l;
    #pragma unroll
    for (int off = 32; off > 0; off >>= 1) m = fmaxf(m, __shfl_xor(m, off, 64));
    float e = __expf(l - m);
    float ssum = e;
    #pragma unroll
    for (int off = 32; off > 0; off >>= 1) ssum += __shfl_xor(ssum, off, 64);
    outp[(size_t)b * O_ + tid] = e / ssum;
  }
}

extern "C" void kernel_launch(void* const* d_in, const int* in_sizes, int n_in,
                              void* d_out, int out_size, void* d_ws, size_t ws_size,
                              hipStream_t stream) {
  (void)in_sizes; (void)n_in; (void)out_size; (void)ws_size;
  const float* X   = (const float*)d_in[0];
  const float* Wxi = (const float*)d_in[1];
  const float* Whi = (const float*)d_in[2];
  const float* bi  = (const float*)d_in[3];
  const float* Wxf = (const float*)d_in[4];
  const float* Whf = (const float*)d_in[5];
  const float* bfv = (const float*)d_in[6];
  const float* Wxo = (const float*)d_in[7];
  const float* Who = (const float*)d_in[8];
  const float* bo  = (const float*)d_in[9];
  const float* Wxc = (const float*)d_in[10];
  const float* Whc = (const float*)d_in[11];
  const float* bc  = (const float*)d_in[12];
  const float* Wo1 = (const float*)d_in[13];
  const float* bo1 = (const float*)d_in[14];
  const float* Wo2 = (const float*)d_in[15];
  const float* bo2 = (const float*)d_in[16];
  float* out = (float*)d_out;

  unsigned* flags = (unsigned*)d_ws;                      // 1 KB of per-WG flags
  unsigned* Hbuf  = (unsigned*)((char*)d_ws + 1024);      // 2 x 128KB fragment images

  hipMemsetAsync(d_ws, 0, 1024, stream);  // reset flags every call
  hipLaunchKernelGGL(lstm_rec, dim3(NGRP * WGPG), dim3(256), 0, stream,
                     X, Wxi, Whi, bi, Wxf, Whf, bfv, Wxo, Who, bo, Wxc, Whc, bc,
                     out, flags, Hbuf);
  hipLaunchKernelGGL(lstm_head, dim3(B_), dim3(256), 0, stream,
                     out + B_ * O_, Wo1, bo1, Wo2, bo2, out);
}

// Round 5
// 2291.503 us; speedup vs baseline: 10.9900x; 1.1795x over previous
//
#include <hip/hip_runtime.h>

#define B_   128
#define S_   1024
#define I_   256
#define H_   512
#define L1_  256
#define O_   64

#define NGRP 8     // batch groups
#define WGPG 32    // workgroups per group (sync cohort)
#define MB   16    // batches per group
#define NH   16    // hidden units per WG
#define NCOL 64    // gate columns per WG (4 gates x NH)
#define SX   8     // K-steps for X part (256/32)
#define SH   16    // K-steps for H part (512/32)

#define HB_UINTS_PER_BUF 32768   // 8 groups x 4096 uints (16KB fragment image per group)

typedef __attribute__((ext_vector_type(8))) short short8;
typedef __attribute__((ext_vector_type(4))) float f4;
typedef __attribute__((ext_vector_type(4))) unsigned u32x4;

__device__ __forceinline__ unsigned short f2bf(float x) {
  unsigned u = __builtin_bit_cast(unsigned, x);
  u += 0x7FFFu + ((u >> 16) & 1u);   // RNE
  return (unsigned short)(u >> 16);
}

__device__ __forceinline__ f4 mfma_bf16(short8 a, short8 b, f4 c) {
  asm("v_mfma_f32_16x16x32_bf16 %0, %1, %2, %0" : "+v"(c) : "v"(a), "v"(b));
  return c;
}

// Persistent recurrent kernel: 256 WGs = 256 CUs (1/CU via LDS+grid), 256 thr.
// R5 = R4 + race fix: speculative flag pre-load is now fail-safe (init 0 via "+v"),
// consumed only through a data-dependent waitcnt asm + sched_barrier(0) (rule #18:
// hipcc hoists register-only ops past inline-asm waitcnt without a data dep).
__global__ __launch_bounds__(256, 1)
void lstm_rec(const float* __restrict__ X,
              const float* __restrict__ Wxi, const float* __restrict__ Whi, const float* __restrict__ bi,
              const float* __restrict__ Wxf, const float* __restrict__ Whf, const float* __restrict__ bfp,
              const float* __restrict__ Wxo, const float* __restrict__ Who, const float* __restrict__ bop,
              const float* __restrict__ Wxc, const float* __restrict__ Whc, const float* __restrict__ bcp,
              float* __restrict__ out, unsigned* __restrict__ flags,
              unsigned* __restrict__ xslots, unsigned* __restrict__ Hbuf)
{
  // Fragment layout (verified R1-R3): element (k,col) -> lane=((k&31)>>3)*16+col, e=k&7.
  __shared__ unsigned short WhF[4][SH][64][8];  // 64 KB (dead after hoist)
  __shared__ unsigned short WxF[4][SX][64][8];  // 32 KB (dead after hoist; reused as AsX[2])
  __shared__ unsigned short AsH[SH][64][8];     // 16 KB  H A-fragments
  __shared__ float Ps[MB][NCOL];                // 4 KB   pre-activations
  __shared__ float bias_s[NCOL];
  __shared__ int go_s;
  __shared__ int mode_s;

  const int tid  = threadIdx.x;
  const int lane = tid & 63;
  const int wv   = tid >> 6;        // wave id == gate id
  const int g    = blockIdx.x & 7;  // batch group
  const int jg   = blockIdx.x >> 3; // hidden block 0..31
  const int j0   = jg * NH;
  const int b0   = g * MB;

  // ---- post our XCD id ASAP (s_getreg, m09 technique) ----
  unsigned xcc;
  asm volatile("s_getreg_b32 %0, hwreg(HW_REG_XCC_ID)" : "=s"(xcc));
  xcc &= 15u;
  if (tid == 0)
    __hip_atomic_store(xslots + g * 32 + jg, xcc + 1u,
                       __ATOMIC_RELAXED, __HIP_MEMORY_SCOPE_AGENT);

  // ---- issue X(t=0) loads NOW; they complete during weight packing ----
  const int idxA = tid, idxB = 256 + tid;
  const int sA = idxA >> 6, posA = idxA & 63;
  const int sB = idxB >> 6, posB = idxB & 63;
  const int offA = (sA * 64 + posA) * 8;     // ushort offset of 16B chunk in AsX buf
  const int offB = (sB * 64 + posB) * 8;
  const float* bpa = X + (size_t)(b0 + (posA & 15)) * S_ * I_ + (sA * 32 + (posA >> 4) * 8);
  const float* bpb = X + (size_t)(b0 + (posB & 15)) * S_ * I_ + (sB * 32 + (posB >> 4) * 8);
  float4 ra0 = *(const float4*)(bpa);
  float4 ra1 = *(const float4*)(bpa + 4);
  float4 rb0 = *(const float4*)(bpb);
  float4 rb1 = *(const float4*)(bpb + 4);

  const float* Whg[4] = {Whi, Whf, Who, Whc};
  const float* Wxg[4] = {Wxi, Wxf, Wxo, Wxc};
  const float* bg[4]  = {bi, bfp, bop, bcp};

  // ---- one-time: pack weight slices into LDS as bf16 B-fragments ----
  for (int gate = 0; gate < 4; ++gate) {
    const float* Wp = Whg[gate];
    for (int it = 0; it < 32; ++it) {
      int idx = it * 256 + tid;
      int k = idx >> 4, c = idx & 15;
      WhF[gate][k >> 5][((k & 31) >> 3) * 16 + c][k & 7] = f2bf(Wp[(size_t)k * H_ + j0 + c]);
    }
    const float* Xp = Wxg[gate];
    for (int it = 0; it < 16; ++it) {
      int idx = it * 256 + tid;
      int k = idx >> 4, c = idx & 15;
      WxF[gate][k >> 5][((k & 31) >> 3) * 16 + c][k & 7] = f2bf(Xp[(size_t)k * H_ + j0 + c]);
    }
  }
  if (tid < NCOL) bias_s[tid] = bg[tid >> 4][j0 + (tid & 15)];
  if (tid == 0) go_s = 0;
  __syncthreads();

  // ---- hoist this wave's B-fragments into VGPRs (96 VGPR/lane) ----
  short8 wx[SX], wh[SH];
  #pragma unroll
  for (int s = 0; s < SX; ++s) wx[s] = *(const short8*)&WxF[wv][s][lane][0];
  #pragma unroll
  for (int s = 0; s < SH; ++s) wh[s] = *(const short8*)&WhF[wv][s][lane][0];

  // ---- XCD handshake: is the whole group on one XCD? (uniform result) ----
  if (wv == 0) {
    unsigned v;
    for (;;) {
      v = __hip_atomic_load(xslots + g * 32 + (lane & 31),
                            __ATOMIC_RELAXED, __HIP_MEMORY_SCOPE_AGENT);
      if (__all((int)(v != 0u))) break;
      __builtin_amdgcn_s_sleep(1);
    }
    unsigned f0 = (unsigned)__shfl((int)v, 0, 64);
    int same = __all((int)(v == f0));
    if (lane == 0) mode_s = same;
  }
  __syncthreads();            // also orders hoist-reads before AsX alias writes
  const bool l2m = (mode_s != 0);

  // ---- stage AsX[0] (t=0) from the prologue loads ----
  unsigned short* axbase = &WxF[0][0][0][0];   // alias: WxF is dead
  const int AXSTRIDE = SX * 64 * 8;
  {
    union { unsigned short us[8]; u32x4 v; } pk;
    pk.us[0]=f2bf(ra0.x); pk.us[1]=f2bf(ra0.y); pk.us[2]=f2bf(ra0.z); pk.us[3]=f2bf(ra0.w);
    pk.us[4]=f2bf(ra1.x); pk.us[5]=f2bf(ra1.y); pk.us[6]=f2bf(ra1.z); pk.us[7]=f2bf(ra1.w);
    *(u32x4*)(axbase + offA) = pk.v;
    pk.us[0]=f2bf(rb0.x); pk.us[1]=f2bf(rb0.y); pk.us[2]=f2bf(rb0.z); pk.us[3]=f2bf(rb0.w);
    pk.us[4]=f2bf(rb1.x); pk.us[5]=f2bf(rb1.y); pk.us[6]=f2bf(rb1.z); pk.us[7]=f2bf(rb1.w);
    *(u32x4*)(axbase + offB) = pk.v;
  }
  __syncthreads();

  float Creg = 0.f;
  const int pb = tid >> 4;
  const int ph = tid & 15;
  unsigned* myflags = flags + g * 32;

  for (int t = 0; t < S_; ++t) {
    const bool last = (t == S_ - 1);

    // ---- speculative flag pre-load; FAIL-SAFE: starts 0 (-> poll path) ----
    unsigned fpre = 0u;
    const unsigned* fp0 = myflags + (lane & 31);
    if (t > 0 && wv == 0)
      asm volatile("global_load_dword %0, %1, off sc0 sc1"
                   : "+v"(fpre) : "v"(fp0) : "memory");

    // ---- X-part MFMAs straight off the loop top (AsX[t&1] staged at t-1) ----
    float bv = bias_s[wv * 16 + (lane & 15)];
    f4 acc = {bv, bv, bv, bv};
    asm("s_nop 1" : "+v"(acc));  // VALU->MFMA srcC hazard guard
    const unsigned short* ax = axbase + (t & 1) * AXSTRIDE;
    #pragma unroll
    for (int s = 0; s < SX; ++s) {
      short8 a = *(const short8*)(ax + (s * 64 + lane) * 8);
      acc = mfma_bf16(a, wx[s], acc);
    }

    // ---- wait for H_t; copy group H image (16KB) -> AsH ----
    if (t > 0) {
      if (wv == 0) {
        // data-dependent drain: compare below CANNOT be hoisted above this
        asm volatile("s_waitcnt vmcnt(0)" : "+v"(fpre) :: "memory");
        __builtin_amdgcn_sched_barrier(0);   // rule #18 fence
        if (!__all((int)(fpre >= (unsigned)t))) {
          for (;;) {
            unsigned v = __hip_atomic_load(fp0, __ATOMIC_RELAXED, __HIP_MEMORY_SCOPE_AGENT);
            if (__all((int)(v >= (unsigned)t))) break;
            __builtin_amdgcn_s_sleep(1);
          }
        }
        if (lane == 0) *(volatile int*)&go_s = (int)t;
      } else {
        while (*(volatile int*)&go_s < (int)t) __builtin_amdgcn_s_sleep(1);
      }
      const u32x4* gp = (const u32x4*)(Hbuf + (size_t)(t & 1) * HB_UINTS_PER_BUF + g * 4096);
      u32x4 r0, r1, r2, r3;
      if (l2m) {
        asm volatile(
          "global_load_dwordx4 %0, %4, off sc0\n\t"
          "global_load_dwordx4 %1, %5, off sc0\n\t"
          "global_load_dwordx4 %2, %6, off sc0\n\t"
          "global_load_dwordx4 %3, %7, off sc0\n\t"
          "s_waitcnt vmcnt(0)"
          : "=&v"(r0), "=&v"(r1), "=&v"(r2), "=&v"(r3)
          : "v"(gp + tid), "v"(gp + tid + 256), "v"(gp + tid + 512), "v"(gp + tid + 768)
          : "memory");
      } else {
        asm volatile(
          "global_load_dwordx4 %0, %4, off sc0 sc1\n\t"
          "global_load_dwordx4 %1, %5, off sc0 sc1\n\t"
          "global_load_dwordx4 %2, %6, off sc0 sc1\n\t"
          "global_load_dwordx4 %3, %7, off sc0 sc1\n\t"
          "s_waitcnt vmcnt(0)"
          : "=&v"(r0), "=&v"(r1), "=&v"(r2), "=&v"(r3)
          : "v"(gp + tid), "v"(gp + tid + 256), "v"(gp + tid + 512), "v"(gp + tid + 768)
          : "memory");
      }
      u32x4* lp = (u32x4*)&AsH[0][0][0];
      lp[tid]       = r0;
      lp[tid + 256] = r1;
      lp[tid + 512] = r2;
      lp[tid + 768] = r3;
    }
    __syncthreads();   // B: AsH ready

    // ---- issue X loads for t+1 (HBM latency hides under H-MFMAs) ----
    if (!last) {
      const float* pa = bpa + (size_t)(t + 1) * I_;
      const float* pb2 = bpb + (size_t)(t + 1) * I_;
      ra0 = *(const float4*)(pa);
      ra1 = *(const float4*)(pa + 4);
      rb0 = *(const float4*)(pb2);
      rb1 = *(const float4*)(pb2 + 4);
    }

    // ---- H-part MFMAs (A from LDS, B from VGPRs) ----
    if (t > 0) {
      #pragma unroll
      for (int s = 0; s < SH; ++s) {
        short8 a = *(const short8*)&AsH[s][lane][0];
        acc = mfma_bf16(a, wh[s], acc);
      }
    }
    asm("s_nop 7\n\ts_nop 7" : "+v"(acc));  // MFMA->VALU read hazard guard
    {
      int col = wv * 16 + (lane & 15);
      int r0i = (lane >> 4) * 4;            // C/D: col=lane&15, row=(lane>>4)*4+e
      Ps[r0i + 0][col] = acc[0];
      Ps[r0i + 1][col] = acc[1];
      Ps[r0i + 2][col] = acc[2];
      Ps[r0i + 3][col] = acc[3];
    }
    __syncthreads();   // C: Ps ready

    // ---- gates (fp32), C update, H emit; then X cvt+stage for t+1 ----
    {
      float pi = Ps[pb][ph];
      float pf = Ps[pb][16 + ph];
      float po = Ps[pb][32 + ph];
      float pc = Ps[pb][48 + ph];
      float Ig = 1.f / (1.f + __expf(-pi));
      float Fg = 1.f / (1.f + __expf(-pf));
      float Og = 1.f / (1.f + __expf(-po));
      float Ct = 1.f - 2.f / (__expf(2.f * pc) + 1.f);   // tanh
      float Cn = Fg * Creg + Ig * Ct;
      Creg = Cn;
      float Hn = (1.f - 2.f / (__expf(2.f * Cn) + 1.f)) + Og;  // tanh(C) + O (addition!)
      if (!last) {
        unsigned hb = f2bf(Hn);
        unsigned other = (unsigned)__shfl_xor((int)hb, 1, 64);
        if ((ph & 1) == 0) {
          unsigned packed = hb | (other << 16);
          int sl = jg >> 1;
          int pos = ((jg & 1) * 2 + (ph >> 3)) * 16 + pb;
          unsigned* dst = Hbuf + (size_t)((t + 1) & 1) * HB_UINTS_PER_BUF + g * 4096
                        + (sl * 64 + pos) * 4 + ((ph & 7) >> 1);
          if (l2m)
            asm volatile("global_store_dword %0, %1, off sc0" :: "v"(dst), "v"(packed) : "memory");
          else
            asm volatile("global_store_dword %0, %1, off sc0 sc1" :: "v"(dst), "v"(packed) : "memory");
        }
      } else {
        out[B_ * O_ + (size_t)(b0 + pb) * H_ + j0 + ph] = Hn;            // Hf
        out[B_ * O_ + B_ * H_ + (size_t)(b0 + pb) * H_ + j0 + ph] = Cn;  // Cf
      }
    }
    if (!last) {
      // cvt + stage X(t+1) into AsX[(t+1)&1] (readers separated by barriers)
      unsigned short* axw = axbase + ((t + 1) & 1) * AXSTRIDE;
      union { unsigned short us[8]; u32x4 v; } pk;
      pk.us[0]=f2bf(ra0.x); pk.us[1]=f2bf(ra0.y); pk.us[2]=f2bf(ra0.z); pk.us[3]=f2bf(ra0.w);
      pk.us[4]=f2bf(ra1.x); pk.us[5]=f2bf(ra1.y); pk.us[6]=f2bf(ra1.z); pk.us[7]=f2bf(ra1.w);
      *(u32x4*)(axw + offA) = pk.v;
      pk.us[0]=f2bf(rb0.x); pk.us[1]=f2bf(rb0.y); pk.us[2]=f2bf(rb0.z); pk.us[3]=f2bf(rb0.w);
      pk.us[4]=f2bf(rb1.x); pk.us[5]=f2bf(rb1.y); pk.us[6]=f2bf(rb1.z); pk.us[7]=f2bf(rb1.w);
      *(u32x4*)(axw + offB) = pk.v;

      __syncthreads();            // D: H stores drained (vmcnt 0) + AsX staged
      if (tid == 0)
        __hip_atomic_store(myflags + jg, (unsigned)(t + 1),
                           __ATOMIC_RELAXED, __HIP_MEMORY_SCOPE_AGENT);
    }
  }
}

// Output head: h1 = relu(Hf@W_o1+b_o1); out = softmax(h1@W_o2+b_o2). One WG per batch row.
__global__ __launch_bounds__(256, 1)
void lstm_head(const float* __restrict__ Hf,
               const float* __restrict__ Wo1, const float* __restrict__ bo1,
               const float* __restrict__ Wo2, const float* __restrict__ bo2,
               float* __restrict__ outp)
{
  __shared__ float hf[H_];
  __shared__ float h1[L1_];
  const int tid = threadIdx.x;
  const int b = blockIdx.x;
  hf[tid]       = Hf[(size_t)b * H_ + tid];
  hf[tid + 256] = Hf[(size_t)b * H_ + tid + 256];
  __syncthreads();
  float a = bo1[tid];
  #pragma unroll 8
  for (int k = 0; k < H_; ++k) a = fmaf(hf[k], Wo1[(size_t)k * L1_ + tid], a);
  h1[tid] = fmaxf(a, 0.f);
  __syncthreads();
  if (tid < O_) {
    float l = bo2[tid];
    #pragma unroll 8
    for (int j = 0; j < L1_; ++j) l = fmaf(h1[j], Wo2[(size_t)j * O_ + tid], l);
    float m = l;
    #pragma unroll
    for (int off = 32; off > 0; off >>= 1) m = fmaxf(m, __shfl_xor(m, off, 64));
    float e = __expf(l - m);
    float ssum = e;
    #pragma unroll
    for (int off = 32; off > 0; off >>= 1) ssum += __shfl_xor(ssum, off, 64);
    outp[(size_t)b * O_ + tid] = e / ssum;
  }
}

extern "C" void kernel_launch(void* const* d_in, const int* in_sizes, int n_in,
                              void* d_out, int out_size, void* d_ws, size_t ws_size,
                              hipStream_t stream) {
  (void)in_sizes; (void)n_in; (void)out_size; (void)ws_size;
  const float* X   = (const float*)d_in[0];
  const float* Wxi = (const float*)d_in[1];
  const float* Whi = (const float*)d_in[2];
  const float* bi  = (const float*)d_in[3];
  const float* Wxf = (const float*)d_in[4];
  const float* Whf = (const float*)d_in[5];
  const float* bfv = (const float*)d_in[6];
  const float* Wxo = (const float*)d_in[7];
  const float* Who = (const float*)d_in[8];
  const float* bo  = (const float*)d_in[9];
  const float* Wxc = (const float*)d_in[10];
  const float* Whc = (const float*)d_in[11];
  const float* bc  = (const float*)d_in[12];
  const float* Wo1 = (const float*)d_in[13];
  const float* bo1 = (const float*)d_in[14];
  const float* Wo2 = (const float*)d_in[15];
  const float* bo2 = (const float*)d_in[16];
  float* out = (float*)d_out;

  unsigned* flags  = (unsigned*)d_ws;                     // [0,1KB): step flags
  unsigned* xslots = (unsigned*)((char*)d_ws + 1024);     // [1KB,2KB): XCD slots
  unsigned* Hbuf   = (unsigned*)((char*)d_ws + 2048);     // 2 x 128KB fragment images

  hipMemsetAsync(d_ws, 0, 2048, stream);  // reset flags + xslots every call
  hipLaunchKernelGGL(lstm_rec, dim3(NGRP * WGPG), dim3(256), 0, stream,
                     X, Wxi, Whi, bi, Wxf, Whf, bfv, Wxo, Who, bo, Wxc, Whc, bc,
                     out, flags, xslots, Hbuf);
  hipLaunchKernelGGL(lstm_head, dim3(B_), dim3(256), 0, stream,
                     out + B_ * O_, Wo1, bo1, Wo2, bo2, out);
}

// Round 8
// 2164.076 us; speedup vs baseline: 11.6371x; 1.0589x over previous
//
#include <hip/hip_runtime.h>

#define B_   128
#define S_   1024
#define I_   256
#define H_   512
#define L1_  256
#define O_   64

#define NGRP 8     // batch groups
#define WGPG 32    // workgroups per group (sync cohort)
#define MB   16    // batches per group
#define NH   16    // hidden units per WG
#define SX   8     // K-steps for X part (256/32)
#define SH   16    // K-steps for H part (512/32)

#define HB_UINTS_PER_BUF 32768   // 8 groups x 4096 uints (16KB fragment image per group)

typedef __attribute__((ext_vector_type(8))) short short8;
typedef __attribute__((ext_vector_type(4))) float f4;
typedef __attribute__((ext_vector_type(4))) unsigned u32x4;

__device__ __forceinline__ unsigned short f2bf(float x) {
  unsigned u = __builtin_bit_cast(unsigned, x);
  u += 0x7FFFu + ((u >> 16) & 1u);   // RNE
  return (unsigned short)(u >> 16);
}

__device__ __forceinline__ f4 mfma_bf16(short8 a, short8 b, f4 c) {
  asm("v_mfma_f32_16x16x32_bf16 %0, %1, %2, %0" : "+v"(c) : "v"(a), "v"(b));
  return c;
}

// pack 8 fp32 -> 8 bf16 (one 16B fragment chunk) via v_cvt_pk_bf16_f32
__device__ __forceinline__ void stage_chunk(unsigned short* dst, f4 a, f4 b) {
  unsigned d0, d1, d2, d3;
  asm("v_cvt_pk_bf16_f32 %0, %1, %2" : "=v"(d0) : "v"(a[0]), "v"(a[1]));
  asm("v_cvt_pk_bf16_f32 %0, %1, %2" : "=v"(d1) : "v"(a[2]), "v"(a[3]));
  asm("v_cvt_pk_bf16_f32 %0, %1, %2" : "=v"(d2) : "v"(b[0]), "v"(b[1]));
  asm("v_cvt_pk_bf16_f32 %0, %1, %2" : "=v"(d3) : "v"(b[2]), "v"(b[3]));
  u32x4 v = {d0, d1, d2, d3};
  *(u32x4*)dst = v;
}

// R8 = R5's PROVEN sync skeleton (per-WG LLC flags posted by tid0 after barrier D;
// all-wave fail-safe speculative poll; sc0 H-data on same-XCD L2) + compute-local
// wins: interleaved-gate remap (no barrier C), same-wave Psw transpose, 2 MFMA
// accumulators, cvt_pk packing, f4 X loads with compiler-managed waits.
__global__ __launch_bounds__(256, 1)
void lstm_rec(const float* __restrict__ X,
              const float* __restrict__ Wxi, const float* __restrict__ Whi, const float* __restrict__ bi,
              const float* __restrict__ Wxf, const float* __restrict__ Whf, const float* __restrict__ bfp,
              const float* __restrict__ Wxo, const float* __restrict__ Who, const float* __restrict__ bop,
              const float* __restrict__ Wxc, const float* __restrict__ Whc, const float* __restrict__ bcp,
              float* __restrict__ out, unsigned* __restrict__ flags,
              unsigned* __restrict__ xslots, unsigned* __restrict__ Hbuf)
{
  // Fragment layout (verified R1-R5): element (k,col) -> lane=((k&31)>>3)*16+col, e=k&7.
  __shared__ unsigned short WhF[4][SH][64][8];  // 64 KB (dead after hoist)
  __shared__ unsigned short WxF[4][SX][64][8];  // 32 KB (dead after hoist; reused as AsX[2])
  __shared__ unsigned short AsH[SH][64][8];     // 16 KB  H A-fragments
  __shared__ float Psw[4][16][20];              // 5 KB   per-wave P transpose (padded)
  __shared__ int mode_s;

  const int tid  = threadIdx.x;
  const int lane = tid & 63;
  const int wv   = tid >> 6;
  const int g    = blockIdx.x & 7;  // batch group
  const int jg   = blockIdx.x >> 3; // hidden block 0..31
  const int j0   = jg * NH;
  const int b0   = g * MB;

  // ---- post our XCD id (s_getreg, m09 technique) ----
  unsigned xcc;
  asm volatile("s_getreg_b32 %0, hwreg(HW_REG_XCC_ID)" : "=s"(xcc));
  xcc &= 15u;
  if (tid == 0)
    __hip_atomic_store(xslots + g * 32 + jg, xcc + 1u,
                       __ATOMIC_RELAXED, __HIP_MEMORY_SCOPE_AGENT);

  // ---- issue X(t=0) loads; complete during weight packing ----
  const int idxA = tid, idxB = 256 + tid;
  const int sA = idxA >> 6, posA = idxA & 63;
  const int sB = idxB >> 6, posB = idxB & 63;
  const int offA = (sA * 64 + posA) * 8;     // ushort offset of 16B chunk in AsX buf
  const int offB = (sB * 64 + posB) * 8;
  const float* bpa = X + (size_t)(b0 + (posA & 15)) * S_ * I_ + (sA * 32 + (posA >> 4) * 8);
  const float* bpb = X + (size_t)(b0 + (posB & 15)) * S_ * I_ + (sB * 32 + (posB >> 4) * 8);
  f4 ra0 = *(const f4*)(bpa);
  f4 ra1 = *(const f4*)(bpa + 4);
  f4 rb0 = *(const f4*)(bpb);
  f4 rb1 = *(const f4*)(bpb + 4);

  const float* Whg[4] = {Whi, Whf, Who, Whc};
  const float* Wxg[4] = {Wxi, Wxf, Wxo, Wxc};
  const float* bgp[4] = {bi, bfp, bop, bcp};

  // ---- one-time: pack weight slices into LDS as bf16 B-fragments (per-gate) ----
  for (int gate = 0; gate < 4; ++gate) {
    const float* Wp = Whg[gate];
    for (int it = 0; it < 32; ++it) {
      int idx = it * 256 + tid;
      int k = idx >> 4, c = idx & 15;
      WhF[gate][k >> 5][((k & 31) >> 3) * 16 + c][k & 7] = f2bf(Wp[(size_t)k * H_ + j0 + c]);
    }
    const float* Xp = Wxg[gate];
    for (int it = 0; it < 16; ++it) {
      int idx = it * 256 + tid;
      int k = idx >> 4, c = idx & 15;
      WxF[gate][k >> 5][((k & 31) >> 3) * 16 + c][k & 7] = f2bf(Xp[(size_t)k * H_ + j0 + c]);
    }
  }
  if (tid == 0) mode_s = 0;
  __syncthreads();

  // ---- hoist B-fragments with INTERLEAVED-GATE column remap ----
  // wave wv tile column col = gate*4+cc  ->  weight column j0 + wv*4 + cc of gate
  const int colL  = lane & 15;
  const int rgrpL = lane >> 4;
  const int gateL = colL >> 2;
  const int ccL   = colL & 3;
  short8 wx[SX], wh[SH];
  #pragma unroll
  for (int s = 0; s < SX; ++s)
    wx[s] = *(const short8*)&WxF[gateL][s][rgrpL * 16 + wv * 4 + ccL][0];
  #pragma unroll
  for (int s = 0; s < SH; ++s)
    wh[s] = *(const short8*)&WhF[gateL][s][rgrpL * 16 + wv * 4 + ccL][0];
  const float bv = bgp[gateL][j0 + wv * 4 + ccL];

  // ---- XCD handshake (wv0 computes, relay via LDS — R5's proven form) ----
  if (wv == 0) {
    unsigned v;
    for (;;) {
      v = __hip_atomic_load(xslots + g * 32 + (lane & 31),
                            __ATOMIC_RELAXED, __HIP_MEMORY_SCOPE_AGENT);
      if (__all((int)(v != 0u))) break;
      __builtin_amdgcn_s_sleep(1);
    }
    unsigned f0 = (unsigned)__shfl((int)v, 0, 64);
    int same = __all((int)(v == f0));
    if (lane == 0) mode_s = same;
  }
  __syncthreads();            // hoist reads done before AsX alias writes; mode_s ready
  const bool l2m = (mode_s != 0);

  // ---- stage AsX[0] ----
  unsigned short* axbase = &WxF[0][0][0][0];   // alias: WxF is dead after hoist
  const int AXSTRIDE = SX * 64 * 8;
  stage_chunk(axbase + offA, ra0, ra1);
  stage_chunk(axbase + offB, rb0, rb1);
  __syncthreads();

  float Creg = 0.f;
  const int rowG = lane >> 2;          // gate-lane mapping: lane = row*4 + c
  const int cG   = lane & 3;
  const int jG   = j0 + wv * 4 + cG;
  const int dwH  = (((jG >> 5) * 64) + ((jG >> 3) & 3) * 16 + rowG) * 4 + ((jG & 7) >> 1);

  unsigned* myflags = flags + g * 32;          // 32 per-WG flags (R5 layout)
  const unsigned* fp0 = myflags + (lane & 31);

  for (int t = 0; t < S_; ++t) {
    const bool last = (t == S_ - 1);

    // ---- speculative flag pre-load (all waves); FAIL-SAFE init 0 ----
    unsigned fpre = 0u;
    if (t > 0)
      asm volatile("global_load_dword %0, %1, off sc0 sc1"
                   : "+v"(fpre) : "v"(fp0) : "memory");

    // ---- X-part MFMAs (2 accumulators) ----
    f4 acc0 = {bv, bv, bv, bv};
    f4 acc1 = {0.f, 0.f, 0.f, 0.f};
    asm("s_nop 1" : "+v"(acc0));
    asm("s_nop 1" : "+v"(acc1));
    const unsigned short* ax = axbase + (t & 1) * AXSTRIDE;
    #pragma unroll
    for (int s = 0; s < SX; ++s) {
      short8 a = *(const short8*)(ax + (s * 64 + lane) * 8);
      if (s & 1) acc1 = mfma_bf16(a, wx[s], acc1);
      else       acc0 = mfma_bf16(a, wx[s], acc0);
    }

    // ---- wait for H_t (data-dep tie + sched_barrier, R5-proven), load H image ----
    if (t > 0) {
      asm volatile("s_waitcnt vmcnt(0)" : "+v"(fpre) :: "memory");
      __builtin_amdgcn_sched_barrier(0);   // rule #18 fence
      if (!__all((int)(fpre >= (unsigned)t))) {
        for (;;) {
          unsigned v = __hip_atomic_load(fp0, __ATOMIC_RELAXED, __HIP_MEMORY_SCOPE_AGENT);
          if (__all((int)(v >= (unsigned)t))) break;
          __builtin_amdgcn_s_sleep(1);
        }
      }
      const u32x4* gp = (const u32x4*)(Hbuf + (size_t)(t & 1) * HB_UINTS_PER_BUF + g * 4096);
      u32x4 r0, r1, r2, r3;
      if (l2m) {
        asm volatile(
          "global_load_dwordx4 %0, %4, off sc0\n\t"
          "global_load_dwordx4 %1, %5, off sc0\n\t"
          "global_load_dwordx4 %2, %6, off sc0\n\t"
          "global_load_dwordx4 %3, %7, off sc0\n\t"
          "s_waitcnt vmcnt(0)"
          : "=&v"(r0), "=&v"(r1), "=&v"(r2), "=&v"(r3)
          : "v"(gp + tid), "v"(gp + tid + 256), "v"(gp + tid + 512), "v"(gp + tid + 768)
          : "memory");
      } else {
        asm volatile(
          "global_load_dwordx4 %0, %4, off sc0 sc1\n\t"
          "global_load_dwordx4 %1, %5, off sc0 sc1\n\t"
          "global_load_dwordx4 %2, %6, off sc0 sc1\n\t"
          "global_load_dwordx4 %3, %7, off sc0 sc1\n\t"
          "s_waitcnt vmcnt(0)"
          : "=&v"(r0), "=&v"(r1), "=&v"(r2), "=&v"(r3)
          : "v"(gp + tid), "v"(gp + tid + 256), "v"(gp + tid + 512), "v"(gp + tid + 768)
          : "memory");
      }
      u32x4* lp = (u32x4*)&AsH[0][0][0];
      lp[tid]       = r0;
      lp[tid + 256] = r1;
      lp[tid + 512] = r2;
      lp[tid + 768] = r3;
    }
    __syncthreads();   // B: AsH ready

    // ---- issue X(t+1) loads (compiler sinks the waits to stage_chunk below) ----
    if (!last) {
      const float* pa  = bpa + (size_t)(t + 1) * I_;
      const float* pb2 = bpb + (size_t)(t + 1) * I_;
      ra0 = *(const f4*)(pa);
      ra1 = *(const f4*)(pa + 4);
      rb0 = *(const f4*)(pb2);
      rb1 = *(const f4*)(pb2 + 4);
    }

    // ---- H-part MFMAs ----
    if (t > 0) {
      #pragma unroll
      for (int s = 0; s < SH; ++s) {
        short8 a = *(const short8*)&AsH[s][lane][0];
        if (s & 1) acc1 = mfma_bf16(a, wh[s], acc1);
        else       acc0 = mfma_bf16(a, wh[s], acc0);
      }
    }
    asm("s_nop 7" : "+v"(acc0));
    asm("s_nop 7" : "+v"(acc1));
    f4 accs = {acc0[0] + acc1[0], acc0[1] + acc1[1], acc0[2] + acc1[2], acc0[3] + acc1[3]};

    // ---- same-wave transpose through LDS (NO barrier) ----
    *(f4*)&Psw[wv][colL][rgrpL * 4] = accs;
    asm volatile("s_waitcnt lgkmcnt(0)" ::: "memory");
    __builtin_amdgcn_sched_barrier(0);
    float pi = Psw[wv][cG][rowG];
    float pf = Psw[wv][4 + cG][rowG];
    float po = Psw[wv][8 + cG][rowG];
    float pc = Psw[wv][12 + cG][rowG];

    // ---- gates (fp32), C update ----
    float Ig = 1.f / (1.f + __expf(-pi));
    float Fg = 1.f / (1.f + __expf(-pf));
    float Og = 1.f / (1.f + __expf(-po));
    float Ct = 1.f - 2.f / (__expf(2.f * pc) + 1.f);          // tanh
    float Cn = Fg * Creg + Ig * Ct;
    Creg = Cn;
    float Hn = (1.f - 2.f / (__expf(2.f * Cn) + 1.f)) + Og;   // tanh(C) + O (addition!)

    if (!last) {
      // stage X(t+1) into AsX[(t+1)&1] (compiler waits the X loads here)
      unsigned short* axw = axbase + ((t + 1) & 1) * AXSTRIDE;
      stage_chunk(axw + offA, ra0, ra1);
      stage_chunk(axw + offB, rb0, rb1);

      // H pack (cvt_pk pair with lane partner) + store
      float Hp = __shfl_xor(Hn, 1, 64);
      if ((cG & 1) == 0) {
        unsigned packed;
        asm("v_cvt_pk_bf16_f32 %0, %1, %2" : "=v"(packed) : "v"(Hn), "v"(Hp));
        unsigned* dst = Hbuf + (size_t)((t + 1) & 1) * HB_UINTS_PER_BUF + g * 4096 + dwH;
        if (l2m)
          asm volatile("global_store_dword %0, %1, off sc0" :: "v"(dst), "v"(packed) : "memory");
        else
          asm volatile("global_store_dword %0, %1, off sc0 sc1" :: "v"(dst), "v"(packed) : "memory");
      }
      __syncthreads();            // D: ALL waves' H stores + AsX writes drained (R5 protocol)
      if (tid == 0)
        __hip_atomic_store(myflags + jg, (unsigned)(t + 1),
                           __ATOMIC_RELAXED, __HIP_MEMORY_SCOPE_AGENT);
    } else {
      out[B_ * O_ + (size_t)(b0 + rowG) * H_ + jG] = Hn;            // Hf
      out[B_ * O_ + B_ * H_ + (size_t)(b0 + rowG) * H_ + jG] = Cn;  // Cf
    }
  }
}

// Output head: h1 = relu(Hf@W_o1+b_o1); out = softmax(h1@W_o2+b_o2). One WG per batch row.
__global__ __launch_bounds__(256, 1)
void lstm_head(const float* __restrict__ Hf,
               const float* __restrict__ Wo1, const float* __restrict__ bo1,
               const float* __restrict__ Wo2, const float* __restrict__ bo2,
               float* __restrict__ outp)
{
  __shared__ float hf[H_];
  __shared__ float h1[L1_];
  const int tid = threadIdx.x;
  const int b = blockIdx.x;
  hf[tid]       = Hf[(size_t)b * H_ + tid];
  hf[tid + 256] = Hf[(size_t)b * H_ + tid + 256];
  __syncthreads();
  float a = bo1[tid];
  #pragma unroll 8
  for (int k = 0; k < H_; ++k) a = fmaf(hf[k], Wo1[(size_t)k * L1_ + tid], a);
  h1[tid] = fmaxf(a, 0.f);
  __syncthreads();
  if (tid < O_) {
    float l = bo2[tid];
    #pragma unroll 8
    for (int j = 0; j < L1_; ++j) l = fmaf(h1[j], Wo2[(size_t)j * O_ + tid], l);
    float m = l;
    #pragma unroll
    for (int off = 32; off > 0; off >>= 1) m = fmaxf(m, __shfl_xor(m, off, 64));
    float e = __expf(l - m);
    float ssum = e;
    #pragma unroll
    for (int off = 32; off > 0; off >>= 1) ssum += __shfl_xor(ssum, off, 64);
    outp[(size_t)b * O_ + tid] = e / ssum;
  }
}

extern "C" void kernel_launch(void* const* d_in, const int* in_sizes, int n_in,
                              void* d_out, int out_size, void* d_ws, size_t ws_size,
                              hipStream_t stream) {
  (void)in_sizes; (void)n_in; (void)out_size; (void)ws_size;
  const float* X   = (const float*)d_in[0];
  const float* Wxi = (const float*)d_in[1];
  const float* Whi = (const float*)d_in[2];
  const float* bi  = (const float*)d_in[3];
  const float* Wxf = (const float*)d_in[4];
  const float* Whf = (const float*)d_in[5];
  const float* bfv = (const float*)d_in[6];
  const float* Wxo = (const float*)d_in[7];
  const float* Who = (const float*)d_in[8];
  const float* bo  = (const float*)d_in[9];
  const float* Wxc = (const float*)d_in[10];
  const float* Whc = (const float*)d_in[11];
  const float* bc  = (const float*)d_in[12];
  const float* Wo1 = (const float*)d_in[13];
  const float* bo1 = (const float*)d_in[14];
  const float* Wo2 = (const float*)d_in[15];
  const float* bo2 = (const float*)d_in[16];
  float* out = (float*)d_out;

  unsigned* flags  = (unsigned*)d_ws;                     // [0,1KB): per-WG step flags
  unsigned* xslots = (unsigned*)((char*)d_ws + 1024);     // [1KB,2KB): XCD slots
  unsigned* Hbuf   = (unsigned*)((char*)d_ws + 2048);     // 2 x 128KB fragment images

  (void)hipMemsetAsync(d_ws, 0, 2048, stream);  // reset flags + xslots every call
  hipLaunchKernelGGL(lstm_rec, dim3(NGRP * WGPG), dim3(256), 0, stream,
                     X, Wxi, Whi, bi, Wxf, Whf, bfv, Wxo, Who, bo, Wxc, Whc, bc,
                     out, flags, xslots, Hbuf);
  hipLaunchKernelGGL(lstm_head, dim3(B_), dim3(256), 0, stream,
                     out + B_ * O_, Wo1, bo1, Wo2, bo2, out);
}